// Round 11
// baseline (194.133 us; speedup 1.0000x reference)
//
#include <hip/hip_runtime.h>

#define T_SEQ 2048
#define NB 2
#define NH 16
#define HS 64
#define DMODEL 1024
#define NEG_BIG (-3.0e38f)

typedef __attribute__((ext_vector_type(8))) short bf16x8;
typedef __attribute__((ext_vector_type(4))) float f32x4;
#define MFMA16 __builtin_amdgcn_mfma_f32_16x16x32_bf16

__device__ __forceinline__ float bfu2f(unsigned int u) {
    union { unsigned int i; float f; } z; z.i = u << 16; return z.f;
}
__device__ __forceinline__ unsigned short f2bfu(float f) {
    union { float f; unsigned int i; } z; z.f = f;
    unsigned int x = z.i;
    unsigned int r = x + 0x7fffu + ((x >> 16) & 1u);
    return (unsigned short)(r >> 16);
}
__device__ __forceinline__ unsigned int pack_bf16(float a, float b) {
    union { float f; unsigned int u; } x, y; x.f = a; y.f = b;
    return __builtin_amdgcn_perm(y.u + 0x8000u, x.u + 0x8000u, 0x07060302u);
}
__device__ __forceinline__ void gl2lds16(const unsigned short* g, unsigned short* l) {
    __builtin_amdgcn_global_load_lds(
        (const __attribute__((address_space(1))) unsigned int*)g,
        (__attribute__((address_space(3))) unsigned int*)l, 16, 0, 0);
}

// ---------- Pre-pass (merged): z<4 -> W transpose, z=4 -> x convert ----------
__global__ __launch_bounds__(256) void prep_kernel(
    const float4* __restrict__ x4, ushort4* __restrict__ o4,
    const float* __restrict__ W0, const float* __restrict__ W1,
    const float* __restrict__ W2, const float* __restrict__ W3,
    unsigned short* __restrict__ T0, unsigned short* __restrict__ T1,
    unsigned short* __restrict__ T2, unsigned short* __restrict__ T3)
{
    const int t = threadIdx.x;
    if (blockIdx.z < 4) {
        __shared__ float tile[32][33];
        const float* W = (blockIdx.z == 0) ? W0 : (blockIdx.z == 1) ? W1 : (blockIdx.z == 2) ? W2 : W3;
        unsigned short* T = (blockIdx.z == 0) ? T0 : (blockIdx.z == 1) ? T1 : (blockIdx.z == 2) ? T2 : T3;
        const int k0 = blockIdx.x * 32, n0 = blockIdx.y * 32;
        const int r = t >> 5, c = t & 31;
        #pragma unroll
        for (int i = 0; i < 4; ++i)
            tile[r + 8 * i][c] = W[(size_t)(k0 + r + 8 * i) * DMODEL + n0 + c];
        __syncthreads();
        #pragma unroll
        for (int i = 0; i < 4; ++i)
            T[(size_t)(n0 + r + 8 * i) * DMODEL + k0 + c] = f2bfu(tile[c][r + 8 * i]);
    } else {
        const int n4 = NB * T_SEQ * DMODEL / 4;
        for (int i = (blockIdx.y * 32 + blockIdx.x) * 256 + t; i < n4; i += 32 * 32 * 256) {
            float4 f = x4[i];
            ushort4 u;
            u.x = f2bfu(f.x); u.y = f2bfu(f.y); u.z = f2bfu(f.z); u.w = f2bfu(f.w);
            o4[i] = u;
        }
    }
}

// ---------- QKV GEMM + bias + RoPE: 64x128 tile, 8 waves (512 thr), BK=64 ----
// SAME 1536 blocks as r7; 8 waves of 16row x 64col sub-tiles (acc[4], 8
// MFMA/K-step/wave). Per-wave chain halves AND total waves double (r7's
// proven double-win). LDS 24KB unchanged. (r10 failure was ONLY the outproj
// launch line passing 256 threads to a 512-thread kernel; qkv math verified.)
__global__ __launch_bounds__(512) void qkv_mfma_kernel(
    const unsigned short* __restrict__ A,
    const unsigned short* __restrict__ Wqt, const unsigned short* __restrict__ Wkt,
    const unsigned short* __restrict__ Wvt,
    const float* __restrict__ bq, const float* __restrict__ bk, const float* __restrict__ bv,
    unsigned short* __restrict__ qo, unsigned short* __restrict__ ko,
    unsigned short* __restrict__ vt)
{
    __shared__ unsigned short As[64 * 64];
    __shared__ unsigned short Bs[128 * 64];
    const int tid = threadIdx.x;
    const int wave = tid >> 6, lane = tid & 63;
    const int lane15 = lane & 15, quad = lane >> 4;
    const int sw = lane15 & 7;
    const int z = blockIdx.z;
    const unsigned short* Bt = (z == 0) ? Wqt : (z == 1) ? Wkt : Wvt;
    const float* bias = (z == 0) ? bq : (z == 1) ? bk : bv;
    const int m0 = blockIdx.x * 64, n0 = blockIdx.y * 128;
    const int mh = (wave & 3) * 16, nh = (wave >> 2) * 64;
    const int oks0 = ((0 + quad) ^ sw) * 8;
    const int oks1 = ((4 + quad) ^ sw) * 8;

    f32x4 acc[4];
    #pragma unroll
    for (int j = 0; j < 4; ++j) acc[j] = (f32x4){0.f, 0.f, 0.f, 0.f};

    // A: 1 staging iter (64x64), B: 2 iters (128x64), 512 thr x 16B each
    const int srowA = tid >> 3;
    const int soffA = ((tid & 7) ^ (srowA & 7)) * 8;
    int srowB[2], soffB[2];
    #pragma unroll
    for (int it = 0; it < 2; ++it) {
        int cc = it * 512 + tid;
        srowB[it] = cc >> 3;
        soffB[it] = ((cc & 7) ^ (srowB[it] & 7)) * 8;
    }

    for (int kk = 0; kk < 16; ++kk) {
        __syncthreads();
        gl2lds16(A + (size_t)(m0 + srowA) * DMODEL + kk * 64 + soffA, As + tid * 8);
        #pragma unroll
        for (int it = 0; it < 2; ++it) {
            int cc = it * 512 + tid;
            gl2lds16(Bt + (size_t)(n0 + srowB[it]) * DMODEL + kk * 64 + soffB[it], Bs + cc * 8);
        }
        __syncthreads();
        #pragma unroll
        for (int ks = 0; ks < 2; ++ks) {
            const int o = ks ? oks1 : oks0;
            bf16x8 af = *(const bf16x8*)(As + (mh + lane15) * 64 + o);
            bf16x8 bfr[4];
            #pragma unroll
            for (int j = 0; j < 4; ++j)
                bfr[j] = *(const bf16x8*)(Bs + (nh + j * 16 + lane15) * 64 + o);
            #pragma unroll
            for (int j = 0; j < 4; ++j)
                acc[j] = MFMA16(af, bfr[j], acc[j], 0, 0, 0);
        }
    }

    const int n0c = n0 + nh;
    const int head = n0c >> 6;
    const float bj0 = bias[n0c + lane15];
    const float bj1 = bias[n0c + 16 + lane15];
    const float bj2 = bias[n0c + 32 + lane15];
    const float bj3 = bias[n0c + 48 + lane15];

    if (z < 2) {
        unsigned short* outp = (z == 0) ? qo : ko;
        const float osc = (z == 0) ? 0.18033688011112042f : 1.0f;  // (1/8)*log2(e)
        const float inv0 = __builtin_exp2f(-(float)(lane15)      * 0.41524101186092029f);
        const float inv1 = __builtin_exp2f(-(float)(lane15 + 16) * 0.41524101186092029f);
        #pragma unroll
        for (int r = 0; r < 4; ++r) {
            int tok = m0 + mh + quad * 4 + r;
            int bb = tok >> 11, t = tok & (T_SEQ - 1);
            float a0 = (float)t * inv0, a1 = (float)t * inv1;
            float sn0, cs0, sn1, cs1;
            __sincosf(a0, &sn0, &cs0);
            __sincosf(a1, &sn1, &cs1);
            float v0 = acc[0][r] + bj0, v1 = acc[1][r] + bj1;
            float v2 = acc[2][r] + bj2, v3 = acc[3][r] + bj3;
            size_t base = ((size_t)(bb * NH + head) * T_SEQ + t) * HS;
            outp[base + lane15]      = f2bfu((v0 * cs0 - v2 * sn0) * osc);
            outp[base + 16 + lane15] = f2bfu((v1 * cs1 - v3 * sn1) * osc);
            outp[base + 32 + lane15] = f2bfu((v2 * cs0 + v0 * sn0) * osc);
            outp[base + 48 + lane15] = f2bfu((v3 * cs1 + v1 * sn1) * osc);
        }
    } else {
        int tok0_ = m0 + mh + quad * 4;
        int bb = tok0_ >> 11, t0 = tok0_ & (T_SEQ - 1);
        #pragma unroll
        for (int j = 0; j < 4; ++j) {
            float bj = (j == 0) ? bj0 : (j == 1) ? bj1 : (j == 2) ? bj2 : bj3;
            ushort4 u;
            u.x = f2bfu(acc[j][0] + bj);
            u.y = f2bfu(acc[j][1] + bj);
            u.z = f2bfu(acc[j][2] + bj);
            u.w = f2bfu(acc[j][3] + bj);
            *(ushort4*)(vt + ((size_t)(bb * NH + head) * HS + j * 16 + lane15) * T_SEQ + t0) = u;
        }
    }
}

// ---------- Flash attention, split-K <=8 tiles/chunk, scale-free softmax ----------
// grid 2560 (bh-fastest), block 256 = 4 waves x 16 q rows each. (r7 winner)
__global__ __launch_bounds__(256, 2) void attn_mfma_kernel(
    const unsigned short* __restrict__ q,   // (BH,T,HS), pre-scaled log2e/8
    const unsigned short* __restrict__ k,   // (BH,T,HS)
    const unsigned short* __restrict__ vt,  // (BH,HS,T)
    const int* __restrict__ mask,
    unsigned short* __restrict__ pO,        // [slot][64 q][64 d] bf16
    float* __restrict__ pl)                 // [slot][64] l fp32
{
    __shared__ unsigned short Ks[64 * 64];      // [key][d], XOR-swizzled chunks
    __shared__ unsigned short Vs[64 * 64];      // [d][key], XOR-swizzled chunks
    __shared__ unsigned short Pt[4][16 * 64];   // per-wave [q][key], XOR-swizzled
    const int tid = threadIdx.x;
    const int wave = tid >> 6, lane = tid & 63;
    const int lane15 = lane & 15, quad = lane >> 4;
    const int sw = lane15 & 7;
    const int oks0 = ((0 + quad) ^ sw) * 8;
    const int oks1 = ((4 + quad) ^ sw) * 8;
    const int bid = blockIdx.x;
    const int bh = bid & 31;
    const int u = 79 - (bid >> 5);              // heavy chunks first
    int qB, c;
    if (u < 8)       { qB = u;                 c = 0; }
    else if (u < 24) { int t = u - 8;  qB = 8  + (t >> 1); c = t & 1; }
    else if (u < 48) { int t = u - 24; qB = 16 + t / 3;    c = t % 3; }
    else             { int t = u - 48; qB = 24 + (t >> 2); c = t & 3; }
    const int slot = bh * 80 + u;
    const int nc  = (qB + 8) >> 3;
    const int len = (qB + nc) / nc;             // ceil((qB+1)/nc)
    const int kt0 = c * len;
    const int kt1 = (kt0 + len - 1 < qB) ? kt0 + len - 1 : qB;
    const int b = bh >> 4;
    const int q0w = qB * 64 + wave * 16;        // this wave's 16 q rows

    const unsigned short* kbase = k  + (size_t)bh * T_SEQ * HS;
    const unsigned short* vbase = vt + (size_t)bh * HS * T_SEQ;

    // Q fragment for this wave's 16 rows
    bf16x8 qf0, qf1;
    {
        const unsigned short* qrow = q + ((size_t)bh * T_SEQ + q0w + lane15) * HS;
        qf0 = *(const bf16x8*)(qrow + quad * 8);
        qf1 = *(const bf16x8*)(qrow + 32 + quad * 8);
    }

    bf16x8 ones;
    #pragma unroll
    for (int i = 0; i < 8; ++i) ones[i] = (short)0x3F80;   // bf16 1.0

    f32x4 accO[4];
    #pragma unroll
    for (int dt = 0; dt < 4; ++dt) accO[dt] = (f32x4){0.f, 0.f, 0.f, 0.f};
    f32x4 acc_l = (f32x4){0.f, 0.f, 0.f, 0.f};

    int srow[2], soff[2];
    #pragma unroll
    for (int it = 0; it < 2; ++it) {
        int cc = it * 256 + tid;
        srow[it] = cc >> 3;
        soff[it] = ((cc & 7) ^ (srow[it] & 7)) * 8;
    }

    for (int kt = kt0; kt <= kt1; ++kt) {
        const int k0 = kt * 64;
        __syncthreads();
        #pragma unroll
        for (int it = 0; it < 2; ++it) {
            int cc = it * 256 + tid;
            gl2lds16(kbase + (size_t)(k0 + srow[it]) * HS + soff[it], Ks + cc * 8);
            gl2lds16(vbase + (size_t)srow[it] * T_SEQ + k0 + soff[it], Vs + cc * 8);
        }
        unsigned long long bal = __ballot(mask[b * T_SEQ + k0 + lane] != 0);
        __syncthreads();

        // S^T[key][q]: this wave's 16 q cols
        f32x4 s[4];
        #pragma unroll
        for (int jt = 0; jt < 4; ++jt) {
            bf16x8 kf0 = *(const bf16x8*)(Ks + (jt * 16 + lane15) * 64 + oks0);
            bf16x8 kf1 = *(const bf16x8*)(Ks + (jt * 16 + lane15) * 64 + oks1);
            f32x4 t_ = (f32x4){0.f, 0.f, 0.f, 0.f};
            t_ = MFMA16(kf0, qf0, t_, 0, 0, 0);
            t_ = MFMA16(kf1, qf1, t_, 0, 0, 0);
            s[jt] = t_;
        }

        const bool need_mask = (k0 + 63 > q0w) || (bal != ~0ull);
        if (need_mask) {
            const int qpos = q0w + lane15;
            #pragma unroll
            for (int jt = 0; jt < 4; ++jt) {
                unsigned int mnib = (unsigned int)(bal >> (jt * 16 + quad * 4)) & 15u;
                #pragma unroll
                for (int r = 0; r < 4; ++r) {
                    int kpos = k0 + jt * 16 + quad * 4 + r;
                    bool ok = (kpos <= qpos) && ((mnib >> r) & 1u);
                    s[jt][r] = ok ? s[jt][r] : NEG_BIG;
                }
            }
        }
        // scale-free softmax: p = exp2(s); shift cancels in O = (P V)/l.
        #pragma unroll
        for (int jt = 0; jt < 4; ++jt)
            #pragma unroll
            for (int r = 0; r < 4; ++r)
                s[jt][r] = exp2f(s[jt][r]);

        // P^T -> Pt[wave][q][key], XOR-swizzled 8-elem chunks (LDS pipe)
        #pragma unroll
        for (int jt = 0; jt < 4; ++jt) {
            unsigned int p01 = pack_bf16(s[jt][0], s[jt][1]);
            unsigned int p23 = pack_bf16(s[jt][2], s[jt][3]);
            int pchunk = (2 * jt + (quad >> 1)) ^ sw;
            int paddr = lane15 * 64 + pchunk * 8 + (quad & 1) * 4;
            *(uint2*)(&Pt[wave][paddr]) = make_uint2(p01, p23);
        }

        bf16x8 pf0 = *(const bf16x8*)(&Pt[wave][lane15 * 64 + oks0]);
        bf16x8 pf1 = *(const bf16x8*)(&Pt[wave][lane15 * 64 + oks1]);
        #pragma unroll
        for (int dt = 0; dt < 4; ++dt) {
            bf16x8 vf0 = *(const bf16x8*)(Vs + (dt * 16 + lane15) * 64 + oks0);
            bf16x8 vf1 = *(const bf16x8*)(Vs + (dt * 16 + lane15) * 64 + oks1);
            accO[dt] = MFMA16(pf0, vf0, accO[dt], 0, 0, 0);
            accO[dt] = MFMA16(pf1, vf1, accO[dt], 0, 0, 0);
        }
        // l[q] = P . 1 on the MFMA pipe (D[q][*] = row sum, replicated per col)
        acc_l = MFMA16(pf0, ones, acc_l, 0, 0, 0);
        acc_l = MFMA16(pf1, ones, acc_l, 0, 0, 0);
    }

    // store raw partial O (bf16) + l (fp32; lane15==0 holds l[q=quad*4+r])
    unsigned short* ob = pO + (size_t)slot * 4096;
    #pragma unroll
    for (int r = 0; r < 4; ++r) {
        int row = wave * 16 + quad * 4 + r;
        #pragma unroll
        for (int dt = 0; dt < 4; ++dt)
            ob[row * 64 + dt * 16 + lane15] = f2bfu(accO[dt][r]);
    }
    if (lane15 == 0) {
        #pragma unroll
        for (int r = 0; r < 4; ++r)
            pl[slot * 64 + wave * 16 + quad * 4 + r] = acc_l[r];
    }
}

// ---------- Combine split-K partials (<=4) -> y (bf16) ----------
__global__ __launch_bounds__(256) void attn_combine_kernel(
    const unsigned short* __restrict__ pO, const float* __restrict__ pl,
    unsigned short* __restrict__ y)
{
    const int qB = blockIdx.x, bh = blockIdx.y;
    const int b = bh >> 4, h = bh & 15;
    const int tid = threadIdx.x;
    const int row = tid >> 2, cb = (tid & 3) * 16;
    const int nch = (qB + 8) >> 3;
    const int p = (qB < 8) ? qB : (qB < 16) ? 8 + 2 * (qB - 8)
               : (qB < 24) ? 24 + 3 * (qB - 16) : 48 + 4 * (qB - 24);
    const int slot0 = bh * 80 + p;

    float L = 0.f;
    for (int ch = 0; ch < nch; ++ch) L += pl[(slot0 + ch) * 64 + row];
    const float invL = 1.0f / L;

    float a[16];
    #pragma unroll
    for (int i = 0; i < 16; ++i) a[i] = 0.f;
    for (int ch = 0; ch < nch; ++ch) {
        const unsigned short* o = pO + (size_t)(slot0 + ch) * 4096 + row * 64 + cb;
        #pragma unroll
        for (int j = 0; j < 4; ++j) {
            ushort4 u = *(const ushort4*)(o + j * 4);
            a[j * 4 + 0] += bfu2f(u.x); a[j * 4 + 1] += bfu2f(u.y);
            a[j * 4 + 2] += bfu2f(u.z); a[j * 4 + 3] += bfu2f(u.w);
        }
    }
    unsigned short* yrow = y + (size_t)(b * T_SEQ + qB * 64 + row) * DMODEL + h * HS + cb;
    #pragma unroll
    for (int j = 0; j < 4; ++j) {
        ushort4 o;
        o.x = f2bfu(a[j * 4 + 0] * invL); o.y = f2bfu(a[j * 4 + 1] * invL);
        o.z = f2bfu(a[j * 4 + 2] * invL); o.w = f2bfu(a[j * 4 + 3] * invL);
        *(ushort4*)(yrow + j * 4) = o;
    }
}

// ---------- Output projection GEMM: 64x128 tile, 8 waves (512 thr), BK=64 ----
// Same 8-wave split as qkv: 512 blocks kept, waves/CU doubled.
__global__ __launch_bounds__(512) void outproj_mfma_kernel(
    const unsigned short* __restrict__ A,
    const unsigned short* __restrict__ Bt,
    const float* __restrict__ bo, float* __restrict__ out)
{
    __shared__ unsigned short As[64 * 64];
    __shared__ unsigned short Bs[128 * 64];
    const int tid = threadIdx.x;
    const int wave = tid >> 6, lane = tid & 63;
    const int lane15 = lane & 15, quad = lane >> 4;
    const int sw = lane15 & 7;
    const int oks0 = ((0 + quad) ^ sw) * 8;
    const int oks1 = ((4 + quad) ^ sw) * 8;
    const int m0 = blockIdx.x * 64, n0 = blockIdx.y * 128;
    const int mh = (wave & 3) * 16, nh = (wave >> 2) * 64;

    f32x4 acc[4];
    #pragma unroll
    for (int j = 0; j < 4; ++j) acc[j] = (f32x4){0.f, 0.f, 0.f, 0.f};

    const int srowA = tid >> 3;
    const int soffA = ((tid & 7) ^ (srowA & 7)) * 8;
    int srowB[2], soffB[2];
    #pragma unroll
    for (int it = 0; it < 2; ++it) {
        int cc = it * 512 + tid;
        srowB[it] = cc >> 3;
        soffB[it] = ((cc & 7) ^ (srowB[it] & 7)) * 8;
    }

    for (int kk = 0; kk < 16; ++kk) {
        __syncthreads();
        gl2lds16(A + (size_t)(m0 + srowA) * DMODEL + kk * 64 + soffA, As + tid * 8);
        #pragma unroll
        for (int it = 0; it < 2; ++it) {
            int cc = it * 512 + tid;
            gl2lds16(Bt + (size_t)(n0 + srowB[it]) * DMODEL + kk * 64 + soffB[it], Bs + cc * 8);
        }
        __syncthreads();
        #pragma unroll
        for (int ks = 0; ks < 2; ++ks) {
            const int o = ks ? oks1 : oks0;
            bf16x8 af = *(const bf16x8*)(As + (mh + lane15) * 64 + o);
            bf16x8 bfr[4];
            #pragma unroll
            for (int j = 0; j < 4; ++j)
                bfr[j] = *(const bf16x8*)(Bs + (nh + j * 16 + lane15) * 64 + o);
            #pragma unroll
            for (int j = 0; j < 4; ++j)
                acc[j] = MFMA16(af, bfr[j], acc[j], 0, 0, 0);
        }
    }

    const int n0c = n0 + nh;
    const float bj0 = bo[n0c + lane15];
    const float bj1 = bo[n0c + 16 + lane15];
    const float bj2 = bo[n0c + 32 + lane15];
    const float bj3 = bo[n0c + 48 + lane15];
    #pragma unroll
    for (int r = 0; r < 4; ++r) {
        int tok = m0 + mh + quad * 4 + r;
        float* orow = out + (size_t)tok * DMODEL + n0c;
        orow[lane15]      = acc[0][r] + bj0;
        orow[16 + lane15] = acc[1][r] + bj1;
        orow[32 + lane15] = acc[2][r] + bj2;
        orow[48 + lane15] = acc[3][r] + bj3;
    }
}

extern "C" void kernel_launch(void* const* d_in, const int* in_sizes, int n_in,
                              void* d_out, int out_size, void* d_ws, size_t ws_size,
                              hipStream_t stream)
{
    const float* x  = (const float*)d_in[0];
    const int* mask = (const int*)d_in[1];
    const float* Wq = (const float*)d_in[2];
    const float* bq = (const float*)d_in[3];
    const float* Wk = (const float*)d_in[4];
    const float* bk = (const float*)d_in[5];
    const float* Wv = (const float*)d_in[6];
    const float* bv = (const float*)d_in[7];
    const float* Wo = (const float*)d_in[8];
    const float* bo = (const float*)d_in[9];

    // workspace layout (u16 units). pO aliases xb/Wqt/Wkt/Wvt (dead after qkv).
    unsigned short* ws = (unsigned short*)d_ws;
    const size_t M1 = 1024 * 1024;
    unsigned short* qw  = ws;               // [0,4)   (BH,T,HS), pre-scaled log2e/8
    unsigned short* kw  = ws + 4 * M1;      // [4,8)
    unsigned short* vtw = ws + 8 * M1;      // [8,12)  (BH,HS,T)
    unsigned short* yw  = ws + 12 * M1;     // [12,16) (B,T,1024)
    unsigned short* Wot = ws + 16 * M1;     // [16,17)
    unsigned short* xb  = ws + 17 * M1;     // [17,21) x bf16
    unsigned short* Wqt = ws + 21 * M1;     // [21,22)
    unsigned short* Wkt = ws + 22 * M1;     // [22,23)
    unsigned short* Wvt = ws + 23 * M1;     // [23,24)
    unsigned short* pO  = ws + 17 * M1;     // [17,27) 2560 slots x 64x64 bf16 (aliases)
    float* pl = (float*)(ws + 27 * M1);     // 2560 x 64 fp32

    prep_kernel<<<dim3(32, 32, 5), 256, 0, stream>>>(
        (const float4*)x, (ushort4*)xb, Wq, Wk, Wv, Wo, Wqt, Wkt, Wvt, Wot);
    qkv_mfma_kernel<<<dim3(64, 8, 3), 512, 0, stream>>>(
        xb, Wqt, Wkt, Wvt, bq, bk, bv, qw, kw, vtw);
    attn_mfma_kernel<<<2560, 256, 0, stream>>>(
        qw, kw, vtw, mask, pO, pl);
    attn_combine_kernel<<<dim3(32, 32), 256, 0, stream>>>(
        pO, pl, yw);
    outproj_mfma_kernel<<<dim3(64, 8), 512, 0, stream>>>(
        yw, Wot, bo, (float*)d_out);
}

// Round 12
// 183.884 us; speedup vs baseline: 1.0557x; 1.0557x over previous
//
#include <hip/hip_runtime.h>

#define T_SEQ 2048
#define NB 2
#define NH 16
#define HS 64
#define DMODEL 1024
#define NEG_BIG (-3.0e38f)

typedef __attribute__((ext_vector_type(8))) short bf16x8;
typedef __attribute__((ext_vector_type(4))) float f32x4;
#define MFMA16 __builtin_amdgcn_mfma_f32_16x16x32_bf16

__device__ __forceinline__ float bfu2f(unsigned int u) {
    union { unsigned int i; float f; } z; z.i = u << 16; return z.f;
}
__device__ __forceinline__ unsigned short f2bfu(float f) {
    union { float f; unsigned int i; } z; z.f = f;
    unsigned int x = z.i;
    unsigned int r = x + 0x7fffu + ((x >> 16) & 1u);
    return (unsigned short)(r >> 16);
}
__device__ __forceinline__ unsigned int pack_bf16(float a, float b) {
    union { float f; unsigned int u; } x, y; x.f = a; y.f = b;
    return __builtin_amdgcn_perm(y.u + 0x8000u, x.u + 0x8000u, 0x07060302u);
}
// 1-instruction f32 pair -> packed bf16 (lo=cvt(a), hi=cvt(b)), RNE.
// Replaces pack_bf16's 3 VALU ops on the attn hot path (T12 primitive).
__device__ __forceinline__ unsigned int cvtpk_bf16(float a, float b) {
    unsigned int r;
    asm("v_cvt_pk_bf16_f32 %0, %1, %2" : "=v"(r) : "v"(a), "v"(b));
    return r;
}
__device__ __forceinline__ void gl2lds16(const unsigned short* g, unsigned short* l) {
    __builtin_amdgcn_global_load_lds(
        (const __attribute__((address_space(1))) unsigned int*)g,
        (__attribute__((address_space(3))) unsigned int*)l, 16, 0, 0);
}

// ---------- Pre-pass (merged): z<4 -> W transpose, z=4 -> x convert ----------
__global__ __launch_bounds__(256) void prep_kernel(
    const float4* __restrict__ x4, ushort4* __restrict__ o4,
    const float* __restrict__ W0, const float* __restrict__ W1,
    const float* __restrict__ W2, const float* __restrict__ W3,
    unsigned short* __restrict__ T0, unsigned short* __restrict__ T1,
    unsigned short* __restrict__ T2, unsigned short* __restrict__ T3)
{
    const int t = threadIdx.x;
    if (blockIdx.z < 4) {
        __shared__ float tile[32][33];
        const float* W = (blockIdx.z == 0) ? W0 : (blockIdx.z == 1) ? W1 : (blockIdx.z == 2) ? W2 : W3;
        unsigned short* T = (blockIdx.z == 0) ? T0 : (blockIdx.z == 1) ? T1 : (blockIdx.z == 2) ? T2 : T3;
        const int k0 = blockIdx.x * 32, n0 = blockIdx.y * 32;
        const int r = t >> 5, c = t & 31;
        #pragma unroll
        for (int i = 0; i < 4; ++i)
            tile[r + 8 * i][c] = W[(size_t)(k0 + r + 8 * i) * DMODEL + n0 + c];
        __syncthreads();
        #pragma unroll
        for (int i = 0; i < 4; ++i)
            T[(size_t)(n0 + r + 8 * i) * DMODEL + k0 + c] = f2bfu(tile[c][r + 8 * i]);
    } else {
        const int n4 = NB * T_SEQ * DMODEL / 4;
        for (int i = (blockIdx.y * 32 + blockIdx.x) * 256 + t; i < n4; i += 32 * 32 * 256) {
            float4 f = x4[i];
            ushort4 u;
            u.x = f2bfu(f.x); u.y = f2bfu(f.y); u.z = f2bfu(f.z); u.w = f2bfu(f.w);
            o4[i] = u;
        }
    }
}

// ---------- QKV GEMM + bias + RoPE: 64x128 tile, BK=64, XOR-swizzled LDS ----------
// grid (64,8,3), block 256 = 4 waves. (r7 winner config — 8-wave variants r9/r11
// were neutral-to-negative; this is the best-measured.)
__global__ __launch_bounds__(256) void qkv_mfma_kernel(
    const unsigned short* __restrict__ A,
    const unsigned short* __restrict__ Wqt, const unsigned short* __restrict__ Wkt,
    const unsigned short* __restrict__ Wvt,
    const float* __restrict__ bq, const float* __restrict__ bk, const float* __restrict__ bv,
    unsigned short* __restrict__ qo, unsigned short* __restrict__ ko,
    unsigned short* __restrict__ vt)
{
    __shared__ unsigned short As[64 * 64];
    __shared__ unsigned short Bs[128 * 64];
    const int tid = threadIdx.x;
    const int wave = tid >> 6, lane = tid & 63;
    const int lane15 = lane & 15, quad = lane >> 4;
    const int sw = lane15 & 7;
    const int z = blockIdx.z;
    const unsigned short* Bt = (z == 0) ? Wqt : (z == 1) ? Wkt : Wvt;
    const float* bias = (z == 0) ? bq : (z == 1) ? bk : bv;
    const int m0 = blockIdx.x * 64, n0 = blockIdx.y * 128;
    const int mh = (wave & 1) * 32, nh = (wave >> 1) * 64;
    const int oks0 = ((0 + quad) ^ sw) * 8;
    const int oks1 = ((4 + quad) ^ sw) * 8;

    f32x4 acc[2][4];
    #pragma unroll
    for (int i = 0; i < 2; ++i)
        #pragma unroll
        for (int j = 0; j < 4; ++j) acc[i][j] = (f32x4){0.f, 0.f, 0.f, 0.f};

    int srow[4], soff[4];
    #pragma unroll
    for (int it = 0; it < 4; ++it) {
        int cc = it * 256 + tid;
        srow[it] = cc >> 3;
        soff[it] = ((cc & 7) ^ (srow[it] & 7)) * 8;
    }

    for (int kk = 0; kk < 16; ++kk) {
        __syncthreads();
        #pragma unroll
        for (int it = 0; it < 2; ++it) {
            int cc = it * 256 + tid;
            gl2lds16(A + (size_t)(m0 + srow[it]) * DMODEL + kk * 64 + soff[it], As + cc * 8);
        }
        #pragma unroll
        for (int it = 0; it < 4; ++it) {
            int cc = it * 256 + tid;
            gl2lds16(Bt + (size_t)(n0 + srow[it]) * DMODEL + kk * 64 + soff[it], Bs + cc * 8);
        }
        __syncthreads();
        #pragma unroll
        for (int ks = 0; ks < 2; ++ks) {
            const int o = ks ? oks1 : oks0;
            bf16x8 af[2], bfr[4];
            #pragma unroll
            for (int i = 0; i < 2; ++i)
                af[i] = *(const bf16x8*)(As + (mh + i * 16 + lane15) * 64 + o);
            #pragma unroll
            for (int j = 0; j < 4; ++j)
                bfr[j] = *(const bf16x8*)(Bs + (nh + j * 16 + lane15) * 64 + o);
            #pragma unroll
            for (int i = 0; i < 2; ++i)
                #pragma unroll
                for (int j = 0; j < 4; ++j)
                    acc[i][j] = MFMA16(af[i], bfr[j], acc[i][j], 0, 0, 0);
        }
    }

    const int n0c = n0 + nh;
    const int head = n0c >> 6;
    const float bj0 = bias[n0c + lane15];
    const float bj1 = bias[n0c + 16 + lane15];
    const float bj2 = bias[n0c + 32 + lane15];
    const float bj3 = bias[n0c + 48 + lane15];

    if (z < 2) {
        unsigned short* outp = (z == 0) ? qo : ko;
        const float osc = (z == 0) ? 0.18033688011112042f : 1.0f;  // (1/8)*log2(e)
        const float inv0 = __builtin_exp2f(-(float)(lane15)      * 0.41524101186092029f);
        const float inv1 = __builtin_exp2f(-(float)(lane15 + 16) * 0.41524101186092029f);
        #pragma unroll
        for (int i = 0; i < 2; ++i) {
            #pragma unroll
            for (int r = 0; r < 4; ++r) {
                int tok = m0 + mh + i * 16 + quad * 4 + r;
                int bb = tok >> 11, t = tok & (T_SEQ - 1);
                float a0 = (float)t * inv0, a1 = (float)t * inv1;
                float sn0, cs0, sn1, cs1;
                __sincosf(a0, &sn0, &cs0);
                __sincosf(a1, &sn1, &cs1);
                float v0 = acc[i][0][r] + bj0, v1 = acc[i][1][r] + bj1;
                float v2 = acc[i][2][r] + bj2, v3 = acc[i][3][r] + bj3;
                size_t base = ((size_t)(bb * NH + head) * T_SEQ + t) * HS;
                outp[base + lane15]      = f2bfu((v0 * cs0 - v2 * sn0) * osc);
                outp[base + 16 + lane15] = f2bfu((v1 * cs1 - v3 * sn1) * osc);
                outp[base + 32 + lane15] = f2bfu((v2 * cs0 + v0 * sn0) * osc);
                outp[base + 48 + lane15] = f2bfu((v3 * cs1 + v1 * sn1) * osc);
            }
        }
    } else {
        #pragma unroll
        for (int i = 0; i < 2; ++i) {
            int tok0_ = m0 + mh + i * 16 + quad * 4;
            int bb = tok0_ >> 11, t0 = tok0_ & (T_SEQ - 1);
            #pragma unroll
            for (int j = 0; j < 4; ++j) {
                float bj = (j == 0) ? bj0 : (j == 1) ? bj1 : (j == 2) ? bj2 : bj3;
                ushort4 u;
                u.x = f2bfu(acc[i][j][0] + bj);
                u.y = f2bfu(acc[i][j][1] + bj);
                u.z = f2bfu(acc[i][j][2] + bj);
                u.w = f2bfu(acc[i][j][3] + bj);
                *(ushort4*)(vt + ((size_t)(bb * NH + head) * HS + j * 16 + lane15) * T_SEQ + t0) = u;
            }
        }
    }
}

// ---------- Flash attention, split-K <=8 tiles/chunk, scale-free softmax ----------
// grid 2560 (bh-fastest), block 256 = 4 waves x 16 q rows each (r7 winner) +
// (a) v_cvt_pk_bf16_f32 P-packing (1 op/pair vs 3 — cuts ~13% of VALU stream)
// (b) s_setprio(1) around MFMA clusters (T5; ~6 independent blocks/CU at
//     different phases = the m191 regime where it pays, not m190 lockstep).
__global__ __launch_bounds__(256, 2) void attn_mfma_kernel(
    const unsigned short* __restrict__ q,   // (BH,T,HS), pre-scaled log2e/8
    const unsigned short* __restrict__ k,   // (BH,T,HS)
    const unsigned short* __restrict__ vt,  // (BH,HS,T)
    const int* __restrict__ mask,
    unsigned short* __restrict__ pO,        // [slot][64 q][64 d] bf16
    float* __restrict__ pl)                 // [slot][64] l fp32
{
    __shared__ unsigned short Ks[64 * 64];      // [key][d], XOR-swizzled chunks
    __shared__ unsigned short Vs[64 * 64];      // [d][key], XOR-swizzled chunks
    __shared__ unsigned short Pt[4][16 * 64];   // per-wave [q][key], XOR-swizzled
    const int tid = threadIdx.x;
    const int wave = tid >> 6, lane = tid & 63;
    const int lane15 = lane & 15, quad = lane >> 4;
    const int sw = lane15 & 7;
    const int oks0 = ((0 + quad) ^ sw) * 8;
    const int oks1 = ((4 + quad) ^ sw) * 8;
    const int bid = blockIdx.x;
    const int bh = bid & 31;
    const int u = 79 - (bid >> 5);              // heavy chunks first
    int qB, c;
    if (u < 8)       { qB = u;                 c = 0; }
    else if (u < 24) { int t = u - 8;  qB = 8  + (t >> 1); c = t & 1; }
    else if (u < 48) { int t = u - 24; qB = 16 + t / 3;    c = t % 3; }
    else             { int t = u - 48; qB = 24 + (t >> 2); c = t & 3; }
    const int slot = bh * 80 + u;
    const int nc  = (qB + 8) >> 3;
    const int len = (qB + nc) / nc;             // ceil((qB+1)/nc)
    const int kt0 = c * len;
    const int kt1 = (kt0 + len - 1 < qB) ? kt0 + len - 1 : qB;
    const int b = bh >> 4;
    const int q0w = qB * 64 + wave * 16;        // this wave's 16 q rows

    const unsigned short* kbase = k  + (size_t)bh * T_SEQ * HS;
    const unsigned short* vbase = vt + (size_t)bh * HS * T_SEQ;

    // Q fragment for this wave's 16 rows
    bf16x8 qf0, qf1;
    {
        const unsigned short* qrow = q + ((size_t)bh * T_SEQ + q0w + lane15) * HS;
        qf0 = *(const bf16x8*)(qrow + quad * 8);
        qf1 = *(const bf16x8*)(qrow + 32 + quad * 8);
    }

    bf16x8 ones;
    #pragma unroll
    for (int i = 0; i < 8; ++i) ones[i] = (short)0x3F80;   // bf16 1.0

    f32x4 accO[4];
    #pragma unroll
    for (int dt = 0; dt < 4; ++dt) accO[dt] = (f32x4){0.f, 0.f, 0.f, 0.f};
    f32x4 acc_l = (f32x4){0.f, 0.f, 0.f, 0.f};

    int srow[2], soff[2];
    #pragma unroll
    for (int it = 0; it < 2; ++it) {
        int cc = it * 256 + tid;
        srow[it] = cc >> 3;
        soff[it] = ((cc & 7) ^ (srow[it] & 7)) * 8;
    }

    for (int kt = kt0; kt <= kt1; ++kt) {
        const int k0 = kt * 64;
        __syncthreads();
        #pragma unroll
        for (int it = 0; it < 2; ++it) {
            int cc = it * 256 + tid;
            gl2lds16(kbase + (size_t)(k0 + srow[it]) * HS + soff[it], Ks + cc * 8);
            gl2lds16(vbase + (size_t)srow[it] * T_SEQ + k0 + soff[it], Vs + cc * 8);
        }
        unsigned long long bal = __ballot(mask[b * T_SEQ + k0 + lane] != 0);
        __syncthreads();

        // S^T[key][q]: this wave's 16 q cols
        f32x4 s[4];
        __builtin_amdgcn_s_setprio(1);
        #pragma unroll
        for (int jt = 0; jt < 4; ++jt) {
            bf16x8 kf0 = *(const bf16x8*)(Ks + (jt * 16 + lane15) * 64 + oks0);
            bf16x8 kf1 = *(const bf16x8*)(Ks + (jt * 16 + lane15) * 64 + oks1);
            f32x4 t_ = (f32x4){0.f, 0.f, 0.f, 0.f};
            t_ = MFMA16(kf0, qf0, t_, 0, 0, 0);
            t_ = MFMA16(kf1, qf1, t_, 0, 0, 0);
            s[jt] = t_;
        }
        __builtin_amdgcn_s_setprio(0);

        const bool need_mask = (k0 + 63 > q0w) || (bal != ~0ull);
        if (need_mask) {
            const int qpos = q0w + lane15;
            #pragma unroll
            for (int jt = 0; jt < 4; ++jt) {
                unsigned int mnib = (unsigned int)(bal >> (jt * 16 + quad * 4)) & 15u;
                #pragma unroll
                for (int r = 0; r < 4; ++r) {
                    int kpos = k0 + jt * 16 + quad * 4 + r;
                    bool ok = (kpos <= qpos) && ((mnib >> r) & 1u);
                    s[jt][r] = ok ? s[jt][r] : NEG_BIG;
                }
            }
        }
        // scale-free softmax: p = exp2(s); shift cancels in O = (P V)/l.
        #pragma unroll
        for (int jt = 0; jt < 4; ++jt)
            #pragma unroll
            for (int r = 0; r < 4; ++r)
                s[jt][r] = exp2f(s[jt][r]);

        // P^T -> Pt[wave][q][key], XOR-swizzled 8-elem chunks (LDS pipe);
        // packing via v_cvt_pk_bf16_f32 (1 VALU/pair).
        #pragma unroll
        for (int jt = 0; jt < 4; ++jt) {
            unsigned int p01 = cvtpk_bf16(s[jt][0], s[jt][1]);
            unsigned int p23 = cvtpk_bf16(s[jt][2], s[jt][3]);
            int pchunk = (2 * jt + (quad >> 1)) ^ sw;
            int paddr = lane15 * 64 + pchunk * 8 + (quad & 1) * 4;
            *(uint2*)(&Pt[wave][paddr]) = make_uint2(p01, p23);
        }

        bf16x8 pf0 = *(const bf16x8*)(&Pt[wave][lane15 * 64 + oks0]);
        bf16x8 pf1 = *(const bf16x8*)(&Pt[wave][lane15 * 64 + oks1]);
        __builtin_amdgcn_s_setprio(1);
        #pragma unroll
        for (int dt = 0; dt < 4; ++dt) {
            bf16x8 vf0 = *(const bf16x8*)(Vs + (dt * 16 + lane15) * 64 + oks0);
            bf16x8 vf1 = *(const bf16x8*)(Vs + (dt * 16 + lane15) * 64 + oks1);
            accO[dt] = MFMA16(pf0, vf0, accO[dt], 0, 0, 0);
            accO[dt] = MFMA16(pf1, vf1, accO[dt], 0, 0, 0);
        }
        // l[q] = P . 1 on the MFMA pipe (D[q][*] = row sum, replicated per col)
        acc_l = MFMA16(pf0, ones, acc_l, 0, 0, 0);
        acc_l = MFMA16(pf1, ones, acc_l, 0, 0, 0);
        __builtin_amdgcn_s_setprio(0);
    }

    // store raw partial O (bf16) + l (fp32; lane15==0 holds l[q=quad*4+r])
    unsigned short* ob = pO + (size_t)slot * 4096;
    #pragma unroll
    for (int r = 0; r < 4; ++r) {
        int row = wave * 16 + quad * 4 + r;
        #pragma unroll
        for (int dt = 0; dt < 4; ++dt)
            ob[row * 64 + dt * 16 + lane15] = f2bfu(accO[dt][r]);
    }
    if (lane15 == 0) {
        #pragma unroll
        for (int r = 0; r < 4; ++r)
            pl[slot * 64 + wave * 16 + quad * 4 + r] = acc_l[r];
    }
}

// ---------- Combine split-K partials (<=4) -> y (bf16) ----------
__global__ __launch_bounds__(256) void attn_combine_kernel(
    const unsigned short* __restrict__ pO, const float* __restrict__ pl,
    unsigned short* __restrict__ y)
{
    const int qB = blockIdx.x, bh = blockIdx.y;
    const int b = bh >> 4, h = bh & 15;
    const int tid = threadIdx.x;
    const int row = tid >> 2, cb = (tid & 3) * 16;
    const int nch = (qB + 8) >> 3;
    const int p = (qB < 8) ? qB : (qB < 16) ? 8 + 2 * (qB - 8)
               : (qB < 24) ? 24 + 3 * (qB - 16) : 48 + 4 * (qB - 24);
    const int slot0 = bh * 80 + p;

    float L = 0.f;
    for (int ch = 0; ch < nch; ++ch) L += pl[(slot0 + ch) * 64 + row];
    const float invL = 1.0f / L;

    float a[16];
    #pragma unroll
    for (int i = 0; i < 16; ++i) a[i] = 0.f;
    for (int ch = 0; ch < nch; ++ch) {
        const unsigned short* o = pO + (size_t)(slot0 + ch) * 4096 + row * 64 + cb;
        #pragma unroll
        for (int j = 0; j < 4; ++j) {
            ushort4 u = *(const ushort4*)(o + j * 4);
            a[j * 4 + 0] += bfu2f(u.x); a[j * 4 + 1] += bfu2f(u.y);
            a[j * 4 + 2] += bfu2f(u.z); a[j * 4 + 3] += bfu2f(u.w);
        }
    }
    unsigned short* yrow = y + (size_t)(b * T_SEQ + qB * 64 + row) * DMODEL + h * HS + cb;
    #pragma unroll
    for (int j = 0; j < 4; ++j) {
        ushort4 o;
        o.x = f2bfu(a[j * 4 + 0] * invL); o.y = f2bfu(a[j * 4 + 1] * invL);
        o.z = f2bfu(a[j * 4 + 2] * invL); o.w = f2bfu(a[j * 4 + 3] * invL);
        *(ushort4*)(yrow + j * 4) = o;
    }
}

// ---------- Output projection GEMM: 64x128 tile, BK=64, XOR-swizzled ----------
// (r7 winner config.)
__global__ __launch_bounds__(256) void outproj_mfma_kernel(
    const unsigned short* __restrict__ A,
    const unsigned short* __restrict__ Bt,
    const float* __restrict__ bo, float* __restrict__ out)
{
    __shared__ unsigned short As[64 * 64];
    __shared__ unsigned short Bs[128 * 64];
    const int tid = threadIdx.x;
    const int wave = tid >> 6, lane = tid & 63;
    const int lane15 = lane & 15, quad = lane >> 4;
    const int sw = lane15 & 7;
    const int oks0 = ((0 + quad) ^ sw) * 8;
    const int oks1 = ((4 + quad) ^ sw) * 8;
    const int m0 = blockIdx.x * 64, n0 = blockIdx.y * 128;
    const int mh = (wave & 1) * 32, nh = (wave >> 1) * 64;

    f32x4 acc[2][4];
    #pragma unroll
    for (int i = 0; i < 2; ++i)
        #pragma unroll
        for (int j = 0; j < 4; ++j) acc[i][j] = (f32x4){0.f, 0.f, 0.f, 0.f};

    int srow[4], soff[4];
    #pragma unroll
    for (int it = 0; it < 4; ++it) {
        int cc = it * 256 + tid;
        srow[it] = cc >> 3;
        soff[it] = ((cc & 7) ^ (srow[it] & 7)) * 8;
    }

    for (int kk = 0; kk < 16; ++kk) {
        __syncthreads();
        #pragma unroll
        for (int it = 0; it < 2; ++it) {
            int cc = it * 256 + tid;
            gl2lds16(A + (size_t)(m0 + srow[it]) * DMODEL + kk * 64 + soff[it], As + cc * 8);
        }
        #pragma unroll
        for (int it = 0; it < 4; ++it) {
            int cc = it * 256 + tid;
            gl2lds16(Bt + (size_t)(n0 + srow[it]) * DMODEL + kk * 64 + soff[it], Bs + cc * 8);
        }
        __syncthreads();
        #pragma unroll
        for (int ks = 0; ks < 2; ++ks) {
            const int o = ks ? oks1 : oks0;
            bf16x8 af[2], bfr[4];
            #pragma unroll
            for (int i = 0; i < 2; ++i)
                af[i] = *(const bf16x8*)(As + (mh + i * 16 + lane15) * 64 + o);
            #pragma unroll
            for (int j = 0; j < 4; ++j)
                bfr[j] = *(const bf16x8*)(Bs + (nh + j * 16 + lane15) * 64 + o);
            #pragma unroll
            for (int i = 0; i < 2; ++i)
                #pragma unroll
                for (int j = 0; j < 4; ++j)
                    acc[i][j] = MFMA16(af[i], bfr[j], acc[i][j], 0, 0, 0);
        }
    }

    const int n0c = n0 + nh;
    const float bj0 = bo[n0c + lane15];
    const float bj1 = bo[n0c + 16 + lane15];
    const float bj2 = bo[n0c + 32 + lane15];
    const float bj3 = bo[n0c + 48 + lane15];
    #pragma unroll
    for (int i = 0; i < 2; ++i) {
        #pragma unroll
        for (int r = 0; r < 4; ++r) {
            int tok = m0 + mh + i * 16 + quad * 4 + r;
            float* orow = out + (size_t)tok * DMODEL + n0c;
            orow[lane15]      = acc[i][0][r] + bj0;
            orow[16 + lane15] = acc[i][1][r] + bj1;
            orow[32 + lane15] = acc[i][2][r] + bj2;
            orow[48 + lane15] = acc[i][3][r] + bj3;
        }
    }
}

extern "C" void kernel_launch(void* const* d_in, const int* in_sizes, int n_in,
                              void* d_out, int out_size, void* d_ws, size_t ws_size,
                              hipStream_t stream)
{
    const float* x  = (const float*)d_in[0];
    const int* mask = (const int*)d_in[1];
    const float* Wq = (const float*)d_in[2];
    const float* bq = (const float*)d_in[3];
    const float* Wk = (const float*)d_in[4];
    const float* bk = (const float*)d_in[5];
    const float* Wv = (const float*)d_in[6];
    const float* bv = (const float*)d_in[7];
    const float* Wo = (const float*)d_in[8];
    const float* bo = (const float*)d_in[9];

    // workspace layout (u16 units). pO aliases xb/Wqt/Wkt/Wvt (dead after qkv).
    unsigned short* ws = (unsigned short*)d_ws;
    const size_t M1 = 1024 * 1024;
    unsigned short* qw  = ws;               // [0,4)   (BH,T,HS), pre-scaled log2e/8
    unsigned short* kw  = ws + 4 * M1;      // [4,8)
    unsigned short* vtw = ws + 8 * M1;      // [8,12)  (BH,HS,T)
    unsigned short* yw  = ws + 12 * M1;     // [12,16) (B,T,1024)
    unsigned short* Wot = ws + 16 * M1;     // [16,17)
    unsigned short* xb  = ws + 17 * M1;     // [17,21) x bf16
    unsigned short* Wqt = ws + 21 * M1;     // [21,22)
    unsigned short* Wkt = ws + 22 * M1;     // [22,23)
    unsigned short* Wvt = ws + 23 * M1;     // [23,24)
    unsigned short* pO  = ws + 17 * M1;     // [17,27) 2560 slots x 64x64 bf16 (aliases)
    float* pl = (float*)(ws + 27 * M1);     // 2560 x 64 fp32

    prep_kernel<<<dim3(32, 32, 5), 256, 0, stream>>>(
        (const float4*)x, (ushort4*)xb, Wq, Wk, Wv, Wo, Wqt, Wkt, Wvt, Wot);
    qkv_mfma_kernel<<<dim3(64, 8, 3), 256, 0, stream>>>(
        xb, Wqt, Wkt, Wvt, bq, bk, bv, qw, kw, vtw);
    attn_mfma_kernel<<<2560, 256, 0, stream>>>(
        qw, kw, vtw, mask, pO, pl);
    attn_combine_kernel<<<dim3(32, 32), 256, 0, stream>>>(
        pO, pl, yw);
    outproj_mfma_kernel<<<dim3(64, 8), 256, 0, stream>>>(
        yw, Wot, bo, (float*)d_out);
}